// Round 1
// 63.266 us; speedup vs baseline: 1.0289x; 1.0289x over previous
//
#include <hip/hip_runtime.h>
#include <math.h>

// Problem constants (from reference)
#define T_LEN   200
#define B_SZ    4096
#define V_SZ    100000
#define PAD_TOK 1

// Geometry: G columns per block, bitmap dedup in LDS.
// Bitmap: ceil(100000/32) = 3125 words/column, padded to 3136 (16B-divisible,
// multiple of 32 -> bank = word % 32, uniform for random tokens).
#define G        4
#define NBLOCKS  (B_SZ / G)            // 1024 blocks
#define NTHREADS 256
#define WSTRIDE  3136                  // words per column bitmap
#define ROWS_PER_ITER (NTHREADS / G)   // 64
#define MAX_K    ((T_LEN + ROWS_PER_ITER - 1) / ROWS_PER_ITER)  // 4

__global__ __launch_bounds__(NTHREADS) void bow_sigmoid_kernel(
    const int*   __restrict__ text,   // [T, B] int32 token ids
    const float* __restrict__ W,      // [1, V]
    const float* __restrict__ bias,   // [1]
    float*       __restrict__ out)    // [B, 1]
{
    // 4 x 3136 x 4B = 49 KB -> 3 blocks/CU (12 waves/CU)
    __shared__ __align__(16) int bitmap[G][WSTRIDE];
    __shared__ float acc[G];

    const int tid = threadIdx.x;
    const int blk = blockIdx.x;

    // XCD swizzle: keep column ranges contiguous per XCD for text L2 locality.
    const int g  = (blk & 7) * (NBLOCKS / 8) + (blk >> 3);
    const int b0 = g * G;

    // Clear bitmap with int4 stores (3136 vec-stores over 256 threads,
    // consecutive addresses -> conflict-free).
    int4* bm4 = (int4*)&bitmap[0][0];
    for (int i = tid; i < (G * WSTRIDE) / 4; i += NTHREADS)
        bm4[i] = make_int4(0, 0, 0, 0);
    if (tid < G) acc[tid] = 0.0f;
    __syncthreads();

    const int c  = tid & (G - 1);   // column within group, 0..3
    const int t0 = tid >> 2;        // starting row, 0..63

    // Issue all token loads up front (independent -> latency overlap).
    int toks[MAX_K];
    #pragma unroll
    for (int k = 0; k < MAX_K; ++k) {
        const int t = t0 + k * ROWS_PER_ITER;
        toks[k] = (t < T_LEN) ? text[t * B_SZ + b0 + c] : PAD_TOK;
    }

    // Dedup via one independent atomicOr per token — no retry loop, no hash.
    // All MAX_K atomics + W gathers pipeline concurrently.
    float sum = 0.0f;
    #pragma unroll
    for (int k = 0; k < MAX_K; ++k) {
        const int tok = toks[k];
        if (tok == PAD_TOK) continue;
        const unsigned bit = 1u << (tok & 31);
        const int old = atomicOr(&bitmap[c][tok >> 5], (int)bit);
        if (!((unsigned)old & bit)) sum += W[tok];   // first sighting only
    }

    // Reduce across lanes sharing column c (lanes c, c+4, ..., c+60):
    // butterfly over lane-id bits 2..5. Preserves mod-4 lane class.
    sum += __shfl_xor(sum, 4, 64);
    sum += __shfl_xor(sum, 8, 64);
    sum += __shfl_xor(sum, 16, 64);
    sum += __shfl_xor(sum, 32, 64);
    if ((tid & 63) < G) atomicAdd(&acc[c], sum);   // one add per wave per column
    __syncthreads();

    if (tid < G) {
        const float s = acc[tid] + bias[0];
        out[b0 + tid] = 1.0f / (1.0f + expf(-s));
    }
}

extern "C" void kernel_launch(void* const* d_in, const int* in_sizes, int n_in,
                              void* d_out, int out_size, void* d_ws, size_t ws_size,
                              hipStream_t stream) {
    const int*   text = (const int*)d_in[0];    // [200, 4096] int32
    const float* W    = (const float*)d_in[1];  // [1, 100000]
    const float* bias = (const float*)d_in[2];  // [1]
    float*       out  = (float*)d_out;          // [4096, 1]

    bow_sigmoid_kernel<<<NBLOCKS, NTHREADS, 0, stream>>>(text, W, bias, out);
}